// Round 1
// baseline (1528.871 us; speedup 1.0000x reference)
//
#include <hip/hip_runtime.h>
#include <hip/hip_bf16.h>

// Mamba block forward, fp32, correctness-first.
// Shapes: B=2, L=2048, D_MODEL=1024, D_INNER=2048, N(state)=64, DT_RANK=64, D_CONV=4.
// Pipeline:
//  1. xz   = hidden @ in_proj_w^T              (4096 x 4096)   [gemm_nt<0>]
//  2. xact = silu(causal_dwconv(x) + conv_b)   (4096 x 2048)   [conv_silu]
//  3. xdbl = xact @ x_proj_w^T                 (4096 x 192)    [gemm_nt<0>]
//  4. dt   = softplus(xdbl[:, :64] @ dt_proj_w^T + dt_proj_b)  [gemm_nt<1>]
//  5. chunked selective scan (32 chunks x 64 steps):
//       pass1 -> per-chunk local end-states + dt sums
//       combine -> carry states across chunks (P = exp(a * sum(dt)))
//       pass2 -> recompute with true h_in, y, skip, silu(z) gate -> g (in dt buffer)
//  6. out  = g @ out_proj_w^T                  (4096 x 1024)   [gemm_nt<0>]

#define L_SEQ   2048
#define D_INNER 2048
#define NSTATE  64
#define DT_RANK 64
#define NPROJ   192     // DT_RANK + 2*NSTATE
#define CHUNK   64
#define NCHUNK  32      // L_SEQ / CHUNK
#define BSZ     2

// ---------------- generic fp32 GEMM: C[M,N] = A[M,K] @ W[N,K]^T ----------------
// EPI: 0 = none, 1 = bias + softplus
template <int EPI>
__global__ __launch_bounds__(256) void gemm_nt(
    const float* __restrict__ A, int lda,
    const float* __restrict__ W,
    const float* __restrict__ bias,
    float* __restrict__ Cmat,
    int M, int N, int K)
{
    __shared__ float As[16][65];
    __shared__ float Ws[16][65];
    const int tid = threadIdx.x;
    const int tx = tid & 15, ty = tid >> 4;
    const int m0 = blockIdx.y * 64, n0 = blockIdx.x * 64;

    float acc[4][4] = {};

    for (int k0 = 0; k0 < K; k0 += 16) {
#pragma unroll
        for (int i = 0; i < 4; ++i) {
            int e = tid + i * 256;
            int r = e >> 4, k = e & 15;
            As[k][r] = A[(size_t)(m0 + r) * lda + k0 + k];
            Ws[k][r] = W[(size_t)(n0 + r) * K + k0 + k];
        }
        __syncthreads();
#pragma unroll
        for (int k = 0; k < 16; ++k) {
            float av[4], wv[4];
#pragma unroll
            for (int i = 0; i < 4; ++i) { av[i] = As[k][ty * 4 + i]; wv[i] = Ws[k][tx * 4 + i]; }
#pragma unroll
            for (int i = 0; i < 4; ++i)
#pragma unroll
                for (int j = 0; j < 4; ++j)
                    acc[i][j] = fmaf(av[i], wv[j], acc[i][j]);
        }
        __syncthreads();
    }

#pragma unroll
    for (int i = 0; i < 4; ++i) {
        const int m = m0 + ty * 4 + i;
#pragma unroll
        for (int j = 0; j < 4; ++j) {
            const int n = n0 + tx * 4 + j;
            float v = acc[i][j];
            if (EPI == 1) {
                v += bias[n];
                v = (v > 20.f) ? v : log1pf(__expf(v));
            }
            Cmat[(size_t)m * N + n] = v;
        }
    }
}

// ---------------- causal depthwise conv (k=4) + bias + SiLU ----------------
// x lives in xz[:, 0:2048] (row stride 4096). Output xact (row stride 2048).
__global__ __launch_bounds__(256) void conv_silu(
    const float* __restrict__ xz, const float* __restrict__ cw,
    const float* __restrict__ cb, float* __restrict__ xact)
{
    const int idx = blockIdx.x * 256 + threadIdx.x;   // (b*L + t)*2048 + d
    const int d = idx & (D_INNER - 1);
    const int bt = idx >> 11;
    const int t = bt & (L_SEQ - 1);

    float acc = cb[d];
#pragma unroll
    for (int k = 0; k < 4; ++k) {
        const int tt = t - 3 + k;
        if (tt >= 0)
            acc = fmaf(xz[(size_t)(bt - t + tt) * 4096 + d], cw[d * 4 + k], acc);
    }
    const float sig = 1.f / (1.f + __expf(-acc));
    xact[idx] = acc * sig;
}

// ---------------- selective scan, pass 1: per-chunk local scan ----------------
// block: 256 threads = 256 consecutive d channels; grid = B * NCHUNK * 8
__global__ __launch_bounds__(256) void scan_pass1(
    const float* __restrict__ dtf, const float* __restrict__ xact,
    const float* __restrict__ xdbl, const float* __restrict__ A_log,
    float* __restrict__ hend, float* __restrict__ dtsum)
{
    const int tid = threadIdx.x;
    const int blk = blockIdx.x;
    const int dblk = blk & 7;
    const int c = (blk >> 3) & (NCHUNK - 1);
    const int b = blk >> 8;
    const int d = dblk * 256 + tid;

    float a[NSTATE];
#pragma unroll
    for (int n = 0; n < NSTATE; ++n) a[n] = -__expf(A_log[d * NSTATE + n]);

    float h[NSTATE];
#pragma unroll
    for (int n = 0; n < NSTATE; ++n) h[n] = 0.f;

    float dts = 0.f;
    const int t0 = c * CHUNK;
#pragma unroll 1
    for (int t = t0; t < t0 + CHUNK; ++t) {
        const int row = b * L_SEQ + t;
        const float dtv = dtf[(size_t)row * D_INNER + d];
        const float uv  = xact[(size_t)row * D_INNER + d];
        const float du = dtv * uv;
        dts += dtv;
        const float* Brow = xdbl + (size_t)row * NPROJ + DT_RANK;   // block-uniform -> s_load
#pragma unroll
        for (int n = 0; n < NSTATE; ++n)
            h[n] = fmaf(__expf(dtv * a[n]), h[n], du * Brow[n]);
    }

    const size_t bd = (size_t)(b * D_INNER + d);
    const size_t base = (bd * NCHUNK + c) * NSTATE;
#pragma unroll
    for (int n = 0; n < NSTATE; ++n) hend[base + n] = h[n];
    dtsum[bd * NCHUNK + c] = dts;
}

// ---------------- scan combine: carry states across chunks ----------------
// thread = (b, d, n); in-place: hend[c] becomes h_in for chunk c.
__global__ __launch_bounds__(256) void scan_combine(
    const float* __restrict__ A_log, float* __restrict__ hend,
    const float* __restrict__ dtsum)
{
    const int idx = blockIdx.x * 256 + threadIdx.x;
    const int n = idx & (NSTATE - 1);
    const size_t bd = (size_t)(idx >> 6);
    const int d = (int)(bd & (D_INNER - 1));
    const float a = -__expf(A_log[d * NSTATE + n]);

    float carry = 0.f;
#pragma unroll 1
    for (int c = 0; c < NCHUNK; ++c) {
        const size_t off = (bd * NCHUNK + c) * NSTATE + n;
        const float local = hend[off];
        const float P = __expf(a * dtsum[bd * NCHUNK + c]);
        hend[off] = carry;
        carry = fmaf(P, carry, local);
    }
}

// ---------------- selective scan, pass 2: recompute + y + skip + gate ----------------
// g aliases the dt buffer (each element read-then-overwritten by the same thread).
__global__ __launch_bounds__(256) void scan_pass2(
    const float* __restrict__ dtf, const float* __restrict__ xact,
    const float* __restrict__ xdbl, const float* __restrict__ A_log,
    const float* __restrict__ hend, const float* __restrict__ xz,
    const float* __restrict__ Dskip, float* __restrict__ g)
{
    const int tid = threadIdx.x;
    const int blk = blockIdx.x;
    const int dblk = blk & 7;
    const int c = (blk >> 3) & (NCHUNK - 1);
    const int b = blk >> 8;
    const int d = dblk * 256 + tid;

    float a[NSTATE];
#pragma unroll
    for (int n = 0; n < NSTATE; ++n) a[n] = -__expf(A_log[d * NSTATE + n]);

    const size_t bd = (size_t)(b * D_INNER + d);
    const size_t base = (bd * NCHUNK + c) * NSTATE;
    float h[NSTATE];
#pragma unroll
    for (int n = 0; n < NSTATE; ++n) h[n] = hend[base + n];

    const float Dv = Dskip[d];
    const int t0 = c * CHUNK;
#pragma unroll 1
    for (int t = t0; t < t0 + CHUNK; ++t) {
        const int row = b * L_SEQ + t;
        const float dtv = dtf[(size_t)row * D_INNER + d];
        const float uv  = xact[(size_t)row * D_INNER + d];
        const float du = dtv * uv;
        const float* Brow = xdbl + (size_t)row * NPROJ + DT_RANK;
        const float* Crow = Brow + NSTATE;
        float y = 0.f;
#pragma unroll
        for (int n = 0; n < NSTATE; ++n) {
            h[n] = fmaf(__expf(dtv * a[n]), h[n], du * Brow[n]);
            y = fmaf(h[n], Crow[n], y);
        }
        const float zv = xz[(size_t)row * 4096 + D_INNER + d];
        const float sig = 1.f / (1.f + __expf(-zv));
        g[(size_t)row * D_INNER + d] = (y + uv * Dv) * (zv * sig);
    }
}

// ---------------- launch ----------------
extern "C" void kernel_launch(void* const* d_in, const int* in_sizes, int n_in,
                              void* d_out, int out_size, void* d_ws, size_t ws_size,
                              hipStream_t stream) {
    const float* hidden    = (const float*)d_in[0];
    const float* in_proj_w = (const float*)d_in[1];
    const float* conv_w    = (const float*)d_in[2];
    const float* conv_b    = (const float*)d_in[3];
    const float* x_proj_w  = (const float*)d_in[4];
    const float* dt_proj_w = (const float*)d_in[5];
    const float* dt_proj_b = (const float*)d_in[6];
    const float* A_log     = (const float*)d_in[7];
    const float* Dskip     = (const float*)d_in[8];
    const float* out_proj_w= (const float*)d_in[9];
    float* out = (float*)d_out;

    const int M = BSZ * L_SEQ;                 // 4096 rows
    float* ws = (float*)d_ws;
    float* xz    = ws;                         // 4096*4096
    float* xact  = xz    + (size_t)M * 4096;   // 4096*2048
    float* dtbuf = xact  + (size_t)M * D_INNER;// 4096*2048 (reused as g)
    float* xdbl  = dtbuf + (size_t)M * D_INNER;// 4096*192
    float* hend  = xdbl  + (size_t)M * NPROJ;  // 2*2048*32*64
    float* dtsum = hend  + (size_t)BSZ * D_INNER * NCHUNK * NSTATE; // 2*2048*32
    const size_t need = ((size_t)(dtsum + (size_t)BSZ * D_INNER * NCHUNK - ws)) * sizeof(float);
    if (ws_size < need) return;  // workspace too small -> fail loudly (zeros)

    // 1. xz = hidden @ in_proj_w^T
    gemm_nt<0><<<dim3(4096 / 64, M / 64), 256, 0, stream>>>(
        hidden, 1024, in_proj_w, nullptr, xz, M, 4096, 1024);

    // 2. causal depthwise conv + silu
    conv_silu<<<(M * D_INNER) / 256, 256, 0, stream>>>(xz, conv_w, conv_b, xact);

    // 3. xdbl = xact @ x_proj_w^T
    gemm_nt<0><<<dim3(NPROJ / 64, M / 64), 256, 0, stream>>>(
        xact, D_INNER, x_proj_w, nullptr, xdbl, M, NPROJ, D_INNER);

    // 4. dt = softplus(xdbl[:, :64] @ dt_proj_w^T + dt_proj_b)
    gemm_nt<1><<<dim3(D_INNER / 64, M / 64), 256, 0, stream>>>(
        xdbl, NPROJ, dt_proj_w, dt_proj_b, dtbuf, M, D_INNER, DT_RANK);

    // 5. chunked selective scan
    scan_pass1<<<BSZ * NCHUNK * (D_INNER / 256), 256, 0, stream>>>(
        dtbuf, xact, xdbl, A_log, hend, dtsum);
    scan_combine<<<(BSZ * D_INNER * NSTATE) / 256, 256, 0, stream>>>(
        A_log, hend, dtsum);
    scan_pass2<<<BSZ * NCHUNK * (D_INNER / 256), 256, 0, stream>>>(
        dtbuf, xact, xdbl, A_log, hend, xz, Dskip, dtbuf);

    // 6. out = g @ out_proj_w^T
    gemm_nt<0><<<dim3(1024 / 64, M / 64), 256, 0, stream>>>(
        dtbuf, D_INNER, out_proj_w, nullptr, out, M, 1024, D_INNER);
}

// Round 5
// 1002.890 us; speedup vs baseline: 1.5245x; 1.5245x over previous
//
#include <hip/hip_runtime.h>
#include <hip/hip_bf16.h>

// Mamba block forward. GEMMs via split-bf16 MFMA (hi/lo decomposition, 3 MFMA
// per K-step -> ~1e-5 relative error, fp32-grade accuracy at bf16 speed).
// Shapes: B=2, L=2048, D_MODEL=1024, D_INNER=2048, N(state)=64, DT_RANK=64, D_CONV=4.

#define L_SEQ   2048
#define D_INNER 2048
#define NSTATE  64
#define DT_RANK 64
#define NPROJ   192     // DT_RANK + 2*NSTATE
#define CHUNK   64
#define NCHUNK  32      // L_SEQ / CHUNK
#define BSZ     2

typedef __bf16 bf16x8 __attribute__((ext_vector_type(8)));
typedef float  f32x4  __attribute__((ext_vector_type(4)));

__device__ __forceinline__ ushort f2bf(float f) {
    uint u = __float_as_uint(f);
    u = (u + 0x7FFFu + ((u >> 16) & 1u)) >> 16;   // RNE
    return (ushort)u;
}
__device__ __forceinline__ float bf2f(ushort s) {
    return __uint_as_float(((uint)s) << 16);
}

// ---------------- split-bf16 MFMA GEMM: C[M,N] = A[M,K] @ W[N,K]^T ----------------
// BM=BN=128, BK=32, 4 waves. EPI: 0 = none, 1 = bias + softplus.
// M must be a multiple of 128, K a multiple of 32. N-edge guarded.
template <int EPI>
__global__ __launch_bounds__(256) void gemm_mfma(
    const float* __restrict__ A, int lda,
    const float* __restrict__ W,
    const float* __restrict__ bias,
    float* __restrict__ Cmat,
    int N, int K)
{
    __shared__ ushort Ah[128][40];   // 32 cols + 8 pad (80B row stride: 2-way banks)
    __shared__ ushort Al[128][40];
    __shared__ ushort Wh[128][40];
    __shared__ ushort Wl[128][40];

    const int tid  = threadIdx.x;
    const int lane = tid & 63;
    const int wid  = tid >> 6;
    const int m0 = blockIdx.y * 128, n0 = blockIdx.x * 128;
    const int wr = (wid >> 1) * 64;          // wave row offset in tile
    const int wc = (wid & 1) * 64;           // wave col offset in tile
    const int fr = lane & 15;                // row/col within a 16x16 frag
    const int kb = (lane >> 4) * 8;          // k-base within frag

    f32x4 acc[4][4] = {};

    for (int k0 = 0; k0 < K; k0 += 32) {
        // ---- stage A and W tiles as bf16 hi/lo ----
#pragma unroll
        for (int i = 0; i < 4; ++i) {
            const int g = tid + i * 256;     // 0..1023 granules of float4
            const int r = g >> 3, c4 = (g & 7) * 4;
            // A tile
            {
                const float4 v = *(const float4*)&A[(size_t)(m0 + r) * lda + k0 + c4];
                ushort h0 = f2bf(v.x), h1 = f2bf(v.y), h2 = f2bf(v.z), h3 = f2bf(v.w);
                ushort4 hv = make_ushort4(h0, h1, h2, h3);
                ushort4 lv = make_ushort4(f2bf(v.x - bf2f(h0)), f2bf(v.y - bf2f(h1)),
                                          f2bf(v.z - bf2f(h2)), f2bf(v.w - bf2f(h3)));
                *(ushort4*)&Ah[r][c4] = hv;
                *(ushort4*)&Al[r][c4] = lv;
            }
            // W tile (guard N edge)
            {
                float4 v = make_float4(0.f, 0.f, 0.f, 0.f);
                if (n0 + r < N) v = *(const float4*)&W[(size_t)(n0 + r) * K + k0 + c4];
                ushort h0 = f2bf(v.x), h1 = f2bf(v.y), h2 = f2bf(v.z), h3 = f2bf(v.w);
                ushort4 hv = make_ushort4(h0, h1, h2, h3);
                ushort4 lv = make_ushort4(f2bf(v.x - bf2f(h0)), f2bf(v.y - bf2f(h1)),
                                          f2bf(v.z - bf2f(h2)), f2bf(v.w - bf2f(h3)));
                *(ushort4*)&Wh[r][c4] = hv;
                *(ushort4*)&Wl[r][c4] = lv;
            }
        }
        __syncthreads();

        // ---- fragments + MFMA ----
        bf16x8 fah[4], fal[4], fwh[4], fwl[4];
#pragma unroll
        for (int m = 0; m < 4; ++m) {
            fah[m] = *(const bf16x8*)&Ah[wr + m * 16 + fr][kb];
            fal[m] = *(const bf16x8*)&Al[wr + m * 16 + fr][kb];
            fwh[m] = *(const bf16x8*)&Wh[wc + m * 16 + fr][kb];
            fwl[m] = *(const bf16x8*)&Wl[wc + m * 16 + fr][kb];
        }
#pragma unroll
        for (int m = 0; m < 4; ++m)
#pragma unroll
            for (int n = 0; n < 4; ++n) {
                acc[m][n] = __builtin_amdgcn_mfma_f32_16x16x32_bf16(fah[m], fwh[n], acc[m][n], 0, 0, 0);
                acc[m][n] = __builtin_amdgcn_mfma_f32_16x16x32_bf16(fal[m], fwh[n], acc[m][n], 0, 0, 0);
                acc[m][n] = __builtin_amdgcn_mfma_f32_16x16x32_bf16(fah[m], fwl[n], acc[m][n], 0, 0, 0);
            }
        __syncthreads();
    }

    // ---- epilogue: C/D layout col=lane&15, row=(lane>>4)*4+reg ----
    const int rbase = (lane >> 4) * 4;
    const int cbase = lane & 15;
#pragma unroll
    for (int m = 0; m < 4; ++m) {
        const int grow = m0 + wr + m * 16 + rbase;
#pragma unroll
        for (int n = 0; n < 4; ++n) {
            const int gcol = n0 + wc + n * 16 + cbase;
            if (gcol < N) {
#pragma unroll
                for (int r = 0; r < 4; ++r) {
                    float v = acc[m][n][r];
                    if (EPI == 1) {
                        v += bias[gcol];
                        v = (v > 20.f) ? v : log1pf(__expf(v));
                    }
                    Cmat[(size_t)(grow + r) * N + gcol] = v;
                }
            }
        }
    }
}

// ---------------- causal depthwise conv (k=4) + bias + SiLU ----------------
__global__ __launch_bounds__(256) void conv_silu(
    const float* __restrict__ xz, const float* __restrict__ cw,
    const float* __restrict__ cb, float* __restrict__ xact)
{
    const int idx = blockIdx.x * 256 + threadIdx.x;   // (b*L + t)*2048 + d
    const int d = idx & (D_INNER - 1);
    const int bt = idx >> 11;
    const int t = bt & (L_SEQ - 1);

    float acc = cb[d];
#pragma unroll
    for (int k = 0; k < 4; ++k) {
        const int tt = t - 3 + k;
        if (tt >= 0)
            acc = fmaf(xz[(size_t)(bt - t + tt) * 4096 + d], cw[d * 4 + k], acc);
    }
    const float sig = 1.f / (1.f + __expf(-acc));
    xact[idx] = acc * sig;
}

// ---------------- selective scan, pass 1: per-chunk local scan ----------------
__global__ __launch_bounds__(256) void scan_pass1(
    const float* __restrict__ dtf, const float* __restrict__ xact,
    const float* __restrict__ xdbl, const float* __restrict__ A_log,
    float* __restrict__ hend, float* __restrict__ dtsum)
{
    const int tid = threadIdx.x;
    const int blk = blockIdx.x;
    const int dblk = blk & 7;
    const int c = (blk >> 3) & (NCHUNK - 1);
    const int b = blk >> 8;
    const int d = dblk * 256 + tid;

    float a[NSTATE];
#pragma unroll
    for (int n = 0; n < NSTATE; ++n) a[n] = -__expf(A_log[d * NSTATE + n]);

    float h[NSTATE];
#pragma unroll
    for (int n = 0; n < NSTATE; ++n) h[n] = 0.f;

    float dts = 0.f;
    const int t0 = c * CHUNK;
#pragma unroll 1
    for (int t = t0; t < t0 + CHUNK; ++t) {
        const int row = b * L_SEQ + t;
        const float dtv = dtf[(size_t)row * D_INNER + d];
        const float uv  = xact[(size_t)row * D_INNER + d];
        const float du = dtv * uv;
        dts += dtv;
        const float* Brow = xdbl + (size_t)row * NPROJ + DT_RANK;
#pragma unroll
        for (int n = 0; n < NSTATE; ++n)
            h[n] = fmaf(__expf(dtv * a[n]), h[n], du * Brow[n]);
    }

    const size_t bd = (size_t)(b * D_INNER + d);
    const size_t base = (bd * NCHUNK + c) * NSTATE;
#pragma unroll
    for (int n = 0; n < NSTATE; ++n) hend[base + n] = h[n];
    dtsum[bd * NCHUNK + c] = dts;
}

// ---------------- scan combine: carry states across chunks ----------------
__global__ __launch_bounds__(256) void scan_combine(
    const float* __restrict__ A_log, float* __restrict__ hend,
    const float* __restrict__ dtsum)
{
    const int idx = blockIdx.x * 256 + threadIdx.x;
    const int n = idx & (NSTATE - 1);
    const size_t bd = (size_t)(idx >> 6);
    const int d = (int)(bd & (D_INNER - 1));
    const float a = -__expf(A_log[d * NSTATE + n]);

    float carry = 0.f;
#pragma unroll 1
    for (int c = 0; c < NCHUNK; ++c) {
        const size_t off = (bd * NCHUNK + c) * NSTATE + n;
        const float local = hend[off];
        const float P = __expf(a * dtsum[bd * NCHUNK + c]);
        hend[off] = carry;
        carry = fmaf(P, carry, local);
    }
}

// ---------------- selective scan, pass 2: recompute + y + skip + gate ----------------
__global__ __launch_bounds__(256) void scan_pass2(
    const float* __restrict__ dtf, const float* __restrict__ xact,
    const float* __restrict__ xdbl, const float* __restrict__ A_log,
    const float* __restrict__ hend, const float* __restrict__ xz,
    const float* __restrict__ Dskip, float* __restrict__ g)
{
    const int tid = threadIdx.x;
    const int blk = blockIdx.x;
    const int dblk = blk & 7;
    const int c = (blk >> 3) & (NCHUNK - 1);
    const int b = blk >> 8;
    const int d = dblk * 256 + tid;

    float a[NSTATE];
#pragma unroll
    for (int n = 0; n < NSTATE; ++n) a[n] = -__expf(A_log[d * NSTATE + n]);

    const size_t bd = (size_t)(b * D_INNER + d);
    const size_t base = (bd * NCHUNK + c) * NSTATE;
    float h[NSTATE];
#pragma unroll
    for (int n = 0; n < NSTATE; ++n) h[n] = hend[base + n];

    const float Dv = Dskip[d];
    const int t0 = c * CHUNK;
#pragma unroll 1
    for (int t = t0; t < t0 + CHUNK; ++t) {
        const int row = b * L_SEQ + t;
        const float dtv = dtf[(size_t)row * D_INNER + d];
        const float uv  = xact[(size_t)row * D_INNER + d];
        const float du = dtv * uv;
        const float* Brow = xdbl + (size_t)row * NPROJ + DT_RANK;
        const float* Crow = Brow + NSTATE;
        float y = 0.f;
#pragma unroll
        for (int n = 0; n < NSTATE; ++n) {
            h[n] = fmaf(__expf(dtv * a[n]), h[n], du * Brow[n]);
            y = fmaf(h[n], Crow[n], y);
        }
        const float zv = xz[(size_t)row * 4096 + D_INNER + d];
        const float sig = 1.f / (1.f + __expf(-zv));
        g[(size_t)row * D_INNER + d] = (y + uv * Dv) * (zv * sig);
    }
}

// ---------------- launch ----------------
extern "C" void kernel_launch(void* const* d_in, const int* in_sizes, int n_in,
                              void* d_out, int out_size, void* d_ws, size_t ws_size,
                              hipStream_t stream) {
    const float* hidden    = (const float*)d_in[0];
    const float* in_proj_w = (const float*)d_in[1];
    const float* conv_w    = (const float*)d_in[2];
    const float* conv_b    = (const float*)d_in[3];
    const float* x_proj_w  = (const float*)d_in[4];
    const float* dt_proj_w = (const float*)d_in[5];
    const float* dt_proj_b = (const float*)d_in[6];
    const float* A_log     = (const float*)d_in[7];
    const float* Dskip     = (const float*)d_in[8];
    const float* out_proj_w= (const float*)d_in[9];
    float* out = (float*)d_out;

    const int M = BSZ * L_SEQ;                 // 4096 rows
    float* ws = (float*)d_ws;
    float* xz    = ws;                         // 4096*4096
    float* xact  = xz    + (size_t)M * 4096;   // 4096*2048
    float* dtbuf = xact  + (size_t)M * D_INNER;// 4096*2048 (reused as g)
    float* xdbl  = dtbuf + (size_t)M * D_INNER;// 4096*192
    float* hend  = xdbl  + (size_t)M * NPROJ;  // 2*2048*32*64
    float* dtsum = hend  + (size_t)BSZ * D_INNER * NCHUNK * NSTATE; // 2*2048*32
    const size_t need = ((size_t)(dtsum + (size_t)BSZ * D_INNER * NCHUNK - ws)) * sizeof(float);
    if (ws_size < need) return;

    // 1. xz = hidden @ in_proj_w^T            (M x 4096, K=1024)
    gemm_mfma<0><<<dim3(4096 / 128, M / 128), 256, 0, stream>>>(
        hidden, 1024, in_proj_w, nullptr, xz, 4096, 1024);

    // 2. causal depthwise conv + silu
    conv_silu<<<(M * D_INNER) / 256, 256, 0, stream>>>(xz, conv_w, conv_b, xact);

    // 3. xdbl = xact @ x_proj_w^T             (M x 192, K=2048)
    gemm_mfma<0><<<dim3(2, M / 128), 256, 0, stream>>>(
        xact, D_INNER, x_proj_w, nullptr, xdbl, NPROJ, D_INNER);

    // 4. dt = softplus(xdbl[:, :64] @ dt_proj_w^T + dt_proj_b)   (M x 2048, K=64)
    gemm_mfma<1><<<dim3(D_INNER / 128, M / 128), 256, 0, stream>>>(
        xdbl, NPROJ, dt_proj_w, dt_proj_b, dtbuf, D_INNER, DT_RANK);

    // 5. chunked selective scan
    scan_pass1<<<BSZ * NCHUNK * (D_INNER / 256), 256, 0, stream>>>(
        dtbuf, xact, xdbl, A_log, hend, dtsum);
    scan_combine<<<(BSZ * D_INNER * NSTATE) / 256, 256, 0, stream>>>(
        A_log, hend, dtsum);
    scan_pass2<<<BSZ * NCHUNK * (D_INNER / 256), 256, 0, stream>>>(
        dtbuf, xact, xdbl, A_log, hend, xz, Dskip, dtbuf);

    // 6. out = g @ out_proj_w^T               (M x 1024, K=2048)
    gemm_mfma<0><<<dim3(1024 / 128, M / 128), 256, 0, stream>>>(
        dtbuf, D_INNER, out_proj_w, nullptr, out, 1024, D_INNER);
}

// Round 7
// 555.837 us; speedup vs baseline: 2.7506x; 1.8043x over previous
//
#include <hip/hip_runtime.h>

// Mamba block forward. GEMMs: split-fp16 MFMA (A = hi+lo fp16 planes, W = fp16
// once; C = Ah*Wh + Al*Wh -> only ~2^-11 W-rounding error). m97 structure:
// global_load_lds(16B) -> linear [128][32] f16 LDS (64B rows) -> ds_read_b128.
// out_proj uses a single-f16 A plane (TERMS=1): g rounding adds ~4e-5 absmax.
// Shapes: B=2, L=2048, D_MODEL=1024, D_INNER=2048, N(state)=64, DT_RANK=64, D_CONV=4.

#define L_SEQ   2048
#define D_INNER 2048
#define NSTATE  64
#define DT_RANK 64
#define CHUNK   64
#define NCHUNK  32
#define BSZ     2
#define MROWS   4096    // BSZ * L_SEQ

typedef _Float16 f16;
typedef _Float16 f16x8 __attribute__((ext_vector_type(8)));
typedef _Float16 f16x4 __attribute__((ext_vector_type(4)));
typedef float    f32x4 __attribute__((ext_vector_type(4)));

__device__ __forceinline__ void gload_lds16(const void* g, void* l) {
    __builtin_amdgcn_global_load_lds(
        (const __attribute__((address_space(1))) void*)g,
        (__attribute__((address_space(3))) void*)l, 16, 0, 0);
}

// ---------------- split-fp16 MFMA GEMM: C[M,N] = A[M,K] @ W[N,K]^T ----------------
// BM=BN=128, BK=32, 4 waves (2x2). TERMS: 1 = Ah only, 2 = Ah+Al.
// EPI: 0 = plain C store; 1 = bias+softplus; 2 = x_proj special (cols<64 ->
// f16 hi/lo aux planes, cols 64..N-1 -> Cmat at col-64, ldc=128).
// M%128==0, K%32==0. W plane must be row-padded to grid coverage.
template <int TERMS, int EPI>
__global__ __launch_bounds__(256) void gemm_f16(
    const f16* __restrict__ Ah, const f16* __restrict__ Al, int lda,
    const f16* __restrict__ Wh, int ldw,
    const float* __restrict__ bias,
    float* __restrict__ Cmat, int ldc,
    f16* __restrict__ auxh, f16* __restrict__ auxl,
    int N, int K)
{
    __shared__ __align__(16) f16 sAh[128][32];
    __shared__ __align__(16) f16 sWh[128][32];
    __shared__ __align__(16) f16 sAl[TERMS == 2 ? 128 : 16][32];

    const int tid  = threadIdx.x;
    const int lane = tid & 63;
    const int wid  = tid >> 6;
    const int m0 = blockIdx.y * 128, n0 = blockIdx.x * 128;
    const int wr = (wid >> 1) * 64;     // wave row offset
    const int wc = (wid & 1) * 64;      // wave col offset
    const int fr = lane & 15;
    const int kb = (lane >> 4) * 8;     // frag k elem offset
    const int l4 = lane >> 2;           // staging row within 16-row chunk
    const int lc = (lane & 3) * 8;      // staging elem offset (16B piece)
    const int rA = wid * 32;            // wave's staging row block

    f32x4 acc[4][4] = {};

    for (int k0 = 0; k0 < K; k0 += 32) {
#pragma unroll
        for (int i = 0; i < 2; ++i) {
            const int r = rA + i * 16;
            const size_t ga = (size_t)(m0 + r + l4) * lda + k0 + lc;
            const size_t gw = (size_t)(n0 + r + l4) * ldw + k0 + lc;
            gload_lds16(&Wh[gw], &sWh[r][0]);
            gload_lds16(&Ah[ga], &sAh[r][0]);
            if constexpr (TERMS == 2) gload_lds16(&Al[ga], &sAl[r][0]);
        }
        __syncthreads();

        f16x8 fah[4], fal[4], fw[4];
#pragma unroll
        for (int m = 0; m < 4; ++m) {
            fah[m] = *(const f16x8*)&sAh[wr + m * 16 + fr][kb];
            fw[m]  = *(const f16x8*)&sWh[wc + m * 16 + fr][kb];
            if constexpr (TERMS == 2) fal[m] = *(const f16x8*)&sAl[wr + m * 16 + fr][kb];
        }
#pragma unroll
        for (int m = 0; m < 4; ++m)
#pragma unroll
            for (int n = 0; n < 4; ++n) {
                acc[m][n] = __builtin_amdgcn_mfma_f32_16x16x32_f16(fah[m], fw[n], acc[m][n], 0, 0, 0);
                if constexpr (TERMS == 2)
                    acc[m][n] = __builtin_amdgcn_mfma_f32_16x16x32_f16(fal[m], fw[n], acc[m][n], 0, 0, 0);
            }
        __syncthreads();
    }

    // C/D layout: col = lane&15, row = (lane>>4)*4 + reg
    const int rbase = (lane >> 4) * 4;
    const int cbase = lane & 15;
#pragma unroll
    for (int m = 0; m < 4; ++m) {
        const int grow = m0 + wr + m * 16 + rbase;
#pragma unroll
        for (int n = 0; n < 4; ++n) {
            const int gcol = n0 + wc + n * 16 + cbase;
            if (gcol < N) {
#pragma unroll
                for (int r = 0; r < 4; ++r) {
                    float v = acc[m][n][r];
                    const size_t rr = (size_t)(grow + r);
                    if constexpr (EPI == 1) {
                        v += bias[gcol];
                        v = (v > 20.f) ? v : log1pf(__expf(v));
                        Cmat[rr * ldc + gcol] = v;
                    } else if constexpr (EPI == 2) {
                        if (gcol < DT_RANK) {
                            const f16 h = (f16)v;
                            auxh[rr * DT_RANK + gcol] = h;
                            auxl[rr * DT_RANK + gcol] = (f16)(v - (float)h);
                        } else {
                            Cmat[rr * ldc + (gcol - DT_RANK)] = v;
                        }
                    } else {
                        Cmat[rr * ldc + gcol] = v;
                    }
                }
            }
        }
    }
}

// ---------------- conversions ----------------
__global__ __launch_bounds__(256) void split_f32(
    const float* __restrict__ src, f16* __restrict__ hi, f16* __restrict__ lo, int n4)
{
    const int i = blockIdx.x * 256 + threadIdx.x;
    if (i >= n4) return;
    const float4 v = ((const float4*)src)[i];
    f16x4 h, l;
    h[0] = (f16)v.x; h[1] = (f16)v.y; h[2] = (f16)v.z; h[3] = (f16)v.w;
    l[0] = (f16)(v.x - (float)h[0]); l[1] = (f16)(v.y - (float)h[1]);
    l[2] = (f16)(v.z - (float)h[2]); l[3] = (f16)(v.w - (float)h[3]);
    ((f16x4*)hi)[i] = h;
    ((f16x4*)lo)[i] = l;
}

// fp32 [N][K] -> fp16 [Npad][K], zero rows >= N. i indexes float4 groups.
__global__ __launch_bounds__(256) void cvt_w(
    const float* __restrict__ src, f16* __restrict__ dst, int N, int kshift, int n4)
{
    const int i = blockIdx.x * 256 + threadIdx.x;
    if (i >= n4) return;
    const int row = i >> (kshift - 2);
    float4 v = make_float4(0.f, 0.f, 0.f, 0.f);
    if (row < N) v = ((const float4*)src)[i];
    f16x4 h;
    h[0] = (f16)v.x; h[1] = (f16)v.y; h[2] = (f16)v.z; h[3] = (f16)v.w;
    ((f16x4*)dst)[i] = h;
}

// ---------------- causal depthwise conv (k=4) + bias + SiLU -> fp16 planes ----------------
__global__ __launch_bounds__(256) void conv_silu(
    const float* __restrict__ xz, const float* __restrict__ cw,
    const float* __restrict__ cb, f16* __restrict__ xh, f16* __restrict__ xl)
{
    const int idx = blockIdx.x * 256 + threadIdx.x;   // (b*L + t)*2048 + d
    const int d = idx & (D_INNER - 1);
    const int bt = idx >> 11;
    const int t = bt & (L_SEQ - 1);

    float acc = cb[d];
#pragma unroll
    for (int k = 0; k < 4; ++k) {
        const int tt = t - 3 + k;
        if (tt >= 0)
            acc = fmaf(xz[(size_t)(bt - t + tt) * 4096 + d], cw[d * 4 + k], acc);
    }
    const float sig = 1.f / (1.f + __expf(-acc));
    const float v = acc * sig;
    const f16 h = (f16)v;
    xh[idx] = h;
    xl[idx] = (f16)(v - (float)h);
}

// ---------------- selective scan ----------------
__global__ __launch_bounds__(256) void scan_pass1(
    const float* __restrict__ dtf, const f16* __restrict__ xh, const f16* __restrict__ xl,
    const float* __restrict__ xbc, const float* __restrict__ A_log,
    float* __restrict__ hend, float* __restrict__ dtsum)
{
    const int tid = threadIdx.x;
    const int blk = blockIdx.x;
    const int dblk = blk & 7;
    const int c = (blk >> 3) & (NCHUNK - 1);
    const int b = blk >> 8;
    const int d = dblk * 256 + tid;

    float a[NSTATE];
#pragma unroll
    for (int n = 0; n < NSTATE; ++n) a[n] = -__expf(A_log[d * NSTATE + n]);

    float h[NSTATE];
#pragma unroll
    for (int n = 0; n < NSTATE; ++n) h[n] = 0.f;

    float dts = 0.f;
    const int t0 = c * CHUNK;
#pragma unroll 1
    for (int t = t0; t < t0 + CHUNK; ++t) {
        const int row = b * L_SEQ + t;
        const size_t off = (size_t)row * D_INNER + d;
        const float dtv = dtf[off];
        const float uv  = (float)xh[off] + (float)xl[off];
        const float du = dtv * uv;
        dts += dtv;
        const float* Brow = xbc + (size_t)row * 128;
#pragma unroll
        for (int n = 0; n < NSTATE; ++n)
            h[n] = fmaf(__expf(dtv * a[n]), h[n], du * Brow[n]);
    }

    const size_t bd = (size_t)(b * D_INNER + d);
    const size_t base = (bd * NCHUNK + c) * NSTATE;
#pragma unroll
    for (int n = 0; n < NSTATE; ++n) hend[base + n] = h[n];
    dtsum[bd * NCHUNK + c] = dts;
}

__global__ __launch_bounds__(256) void scan_combine(
    const float* __restrict__ A_log, float* __restrict__ hend,
    const float* __restrict__ dtsum)
{
    const int idx = blockIdx.x * 256 + threadIdx.x;
    const int n = idx & (NSTATE - 1);
    const size_t bd = (size_t)(idx >> 6);
    const int d = (int)(bd & (D_INNER - 1));
    const float a = -__expf(A_log[d * NSTATE + n]);

    float carry = 0.f;
#pragma unroll 1
    for (int c = 0; c < NCHUNK; ++c) {
        const size_t off = (bd * NCHUNK + c) * NSTATE + n;
        const float local = hend[off];
        const float P = __expf(a * dtsum[bd * NCHUNK + c]);
        hend[off] = carry;
        carry = fmaf(P, carry, local);
    }
}

// pass2 writes g as f16 into the dead x-half of xz rows (disjoint bytes from z reads)
__global__ __launch_bounds__(256) void scan_pass2(
    const float* __restrict__ dtf, const f16* __restrict__ xh, const f16* __restrict__ xl,
    const float* __restrict__ xbc, const float* __restrict__ A_log,
    const float* __restrict__ hend, const float* __restrict__ xz,
    const float* __restrict__ Dskip, f16* __restrict__ gx)
{
    const int tid = threadIdx.x;
    const int blk = blockIdx.x;
    const int dblk = blk & 7;
    const int c = (blk >> 3) & (NCHUNK - 1);
    const int b = blk >> 8;
    const int d = dblk * 256 + tid;

    float a[NSTATE];
#pragma unroll
    for (int n = 0; n < NSTATE; ++n) a[n] = -__expf(A_log[d * NSTATE + n]);

    const size_t bd = (size_t)(b * D_INNER + d);
    const size_t base = (bd * NCHUNK + c) * NSTATE;
    float h[NSTATE];
#pragma unroll
    for (int n = 0; n < NSTATE; ++n) h[n] = hend[base + n];

    const float Dv = Dskip[d];
    const int t0 = c * CHUNK;
#pragma unroll 1
    for (int t = t0; t < t0 + CHUNK; ++t) {
        const int row = b * L_SEQ + t;
        const size_t off = (size_t)row * D_INNER + d;
        const float dtv = dtf[off];
        const float uv  = (float)xh[off] + (float)xl[off];
        const float du = dtv * uv;
        const float* Brow = xbc + (size_t)row * 128;
        const float* Crow = Brow + NSTATE;
        float y = 0.f;
#pragma unroll
        for (int n = 0; n < NSTATE; ++n) {
            h[n] = fmaf(__expf(dtv * a[n]), h[n], du * Brow[n]);
            y = fmaf(h[n], Crow[n], y);
        }
        const float zv = xz[(size_t)row * 4096 + D_INNER + d];
        const float sig = 1.f / (1.f + __expf(-zv));
        const float gv = (y + uv * Dv) * (zv * sig);
        gx[(size_t)row * 8192 + d] = (f16)gv;
    }
}

// ---------------- launch ----------------
extern "C" void kernel_launch(void* const* d_in, const int* in_sizes, int n_in,
                              void* d_out, int out_size, void* d_ws, size_t ws_size,
                              hipStream_t stream) {
    const float* hidden    = (const float*)d_in[0];
    const float* in_proj_w = (const float*)d_in[1];
    const float* conv_w    = (const float*)d_in[2];
    const float* conv_b    = (const float*)d_in[3];
    const float* x_proj_w  = (const float*)d_in[4];
    const float* dt_proj_w = (const float*)d_in[5];
    const float* dt_proj_b = (const float*)d_in[6];
    const float* A_log     = (const float*)d_in[7];
    const float* Dskip     = (const float*)d_in[8];
    const float* out_proj_w= (const float*)d_in[9];
    float* out = (float*)d_out;

    char* base = (char*)d_ws;
    size_t off = 0;
    auto alloc = [&](size_t bytes) -> void* {
        void* p = base + off;
        off += (bytes + 255) & ~(size_t)255;
        return p;
    };
    float* xz    = (float*)alloc((size_t)MROWS * 4096 * 4);      // 64 MB (x-half reused for g f16)
    f16*   xacth = (f16*)  alloc((size_t)MROWS * D_INNER * 2);   // 16 MB
    f16*   xactl = (f16*)  alloc((size_t)MROWS * D_INNER * 2);   // 16 MB
    float* dtb   = (float*)alloc((size_t)MROWS * D_INNER * 4);   // 32 MB
    float* xbc   = (float*)alloc((size_t)MROWS * 128 * 4);       // 2 MB (B|C fp32)
    float* hend  = (float*)alloc((size_t)BSZ * D_INNER * NCHUNK * NSTATE * 4); // 32 MB
    float* dtsum = (float*)alloc((size_t)BSZ * D_INNER * NCHUNK * 4);          // 0.5 MB
    f16*   w_out = (f16*)  alloc((size_t)1024 * 2048 * 2);       // 4 MB
    if (ws_size < off) return;   // total ~166.5 MB (round-1's 171.4 passed)

    // Overlays inside hend: all dead before scan_pass1 first writes hend.
    f16* hidh = (f16*)hend;                       // 8 MB
    f16* hidl = hidh + (size_t)MROWS * 1024;      // 8 MB
    f16* w_in = hidl + (size_t)MROWS * 1024;      // 8 MB
    f16* dth  = w_in + (size_t)4096 * 1024;       // 0.5 MB
    f16* dtl  = dth  + (size_t)MROWS * DT_RANK;   // 0.5 MB
    f16* w_xp = dtl  + (size_t)MROWS * DT_RANK;   // 1 MB (padded 192->256 rows)
    f16* w_dt = w_xp + (size_t)256 * 2048;        // 0.25 MB   => 26.25 MB < 32 MB

    // 0. conversions
    { const int n4 = MROWS * 1024 / 4; split_f32<<<(n4 + 255) / 256, 256, 0, stream>>>(hidden, hidh, hidl, n4); }
    { const int n4 = 4096 * 1024 / 4;  cvt_w<<<(n4 + 255) / 256, 256, 0, stream>>>(in_proj_w,  w_in,  4096, 10, n4); }
    { const int n4 = 256 * 2048 / 4;   cvt_w<<<(n4 + 255) / 256, 256, 0, stream>>>(x_proj_w,   w_xp,   192, 11, n4); }
    { const int n4 = 2048 * 64 / 4;    cvt_w<<<(n4 + 255) / 256, 256, 0, stream>>>(dt_proj_w,  w_dt,  2048,  6, n4); }
    { const int n4 = 1024 * 2048 / 4;  cvt_w<<<(n4 + 255) / 256, 256, 0, stream>>>(out_proj_w, w_out, 1024, 11, n4); }

    // 1. xz = hidden @ in_proj_w^T            (N=4096, K=1024), 2-term
    gemm_f16<2, 0><<<dim3(32, 32), 256, 0, stream>>>(
        hidh, hidl, 1024, w_in, 1024, nullptr, xz, 4096, nullptr, nullptr, 4096, 1024);

    // 2. causal depthwise conv + silu -> fp16 hi/lo planes
    conv_silu<<<(MROWS * D_INNER) / 256, 256, 0, stream>>>(xz, conv_w, conv_b, xacth, xactl);

    // 3. x_dbl = xact @ x_proj_w^T            (N=192, K=2048), 2-term;
    //    dt-slice -> f16 planes, B|C -> xbc fp32 (ldc=128)
    gemm_f16<2, 2><<<dim3(2, 32), 256, 0, stream>>>(
        xacth, xactl, D_INNER, w_xp, D_INNER, nullptr, xbc, 128, dth, dtl, 192, 2048);

    // 4. dt = softplus(dtslice @ dt_proj_w^T + b)   (N=2048, K=64), 2-term
    gemm_f16<2, 1><<<dim3(16, 32), 256, 0, stream>>>(
        dth, dtl, DT_RANK, w_dt, DT_RANK, dt_proj_b, dtb, D_INNER, nullptr, nullptr, D_INNER, DT_RANK);

    // 5. chunked selective scan (g -> f16 in xz x-half, row stride 8192)
    scan_pass1<<<BSZ * NCHUNK * (D_INNER / 256), 256, 0, stream>>>(
        dtb, xacth, xactl, xbc, A_log, hend, dtsum);
    scan_combine<<<(BSZ * D_INNER * NSTATE) / 256, 256, 0, stream>>>(
        A_log, hend, dtsum);
    scan_pass2<<<BSZ * NCHUNK * (D_INNER / 256), 256, 0, stream>>>(
        dtb, xacth, xactl, xbc, A_log, hend, xz, Dskip, (f16*)xz);

    // 6. out = g @ out_proj_w^T               (N=1024, K=2048), 1-term
    gemm_f16<1, 0><<<dim3(8, 32), 256, 0, stream>>>(
        (const f16*)xz, nullptr, 8192, w_out, 2048, nullptr, out, 1024, nullptr, nullptr, 1024, 2048);
}